// Round 7
// baseline (19.800 us; speedup 1.0000x reference)
//
#include <hip/hip_runtime.h>
#include <math.h>

// Gaussian map generator: out[z,y,x] = sum_a amp[a] * exp(-c * |r_voxel - r_atom|^2)
// c = 1/(2 sigma^2), sigma = resolution/(sqrt(2) pi).  res=2 -> c~2.467.
// Pair set: c*d^2 <= 12 (validated rounds 4/6: absmax 0.03125 vs threshold 0.4125).
//
// Round 7: one-node gather, cull traffic halved.  Round 6 (4096 blocks) spent
// ~6us on the cull scan (4096 x 48KB = 196MB of L2 reads).  Now 2048 blocks,
// 32x4x8 tiles, 4 consecutive x-voxels per thread (float4 store).  Per survivor:
// dy^2+dz^2 once per thread + coarse min-|dx| gate over the x-run, exact
// per-voxel gate inside -> same pair set, ~8 inst for non-contributing survivors.

#define EXP_CUT 12.0f
#define CAP     512
#define NTHR    256
#define NBLK    2048

__global__ __launch_bounds__(NTHR)
void gather_gauss(const float* __restrict__ coords,
                  const float* __restrict__ amps,
                  const float* __restrict__ pix,
                  const int* __restrict__ resp,
                  float* __restrict__ out,
                  int n_atoms)
{
    const int NXg = 128, NYg = 128;
    __shared__ float4 alist[CAP];   // {x, y, z, amp}
    __shared__ int    acnt;

    // tile decomposition: 4 x-tiles (32) x 32 y-tiles (4) x 16 z-tiles (8) = 2048
    const int bid = blockIdx.x;
    const int tx = (bid & 3) * 32;
    const int ty = ((bid >> 2) & 31) * 4;
    const int tz = (bid >> 7) * 8;

    if (threadIdx.x == 0) acnt = 0;

    // sigma = res/(sqrt(2) pi); c = 1/(2 sigma^2)
    const float res   = (float)resp[0];
    const float sigma = res / (sqrtf(2.0f) * 3.14159265358979323846f);
    const float c     = 1.0f / (2.0f * sigma * sigma);
    const float R2    = EXP_CUT / c;          // cutoff radius^2 (~4.86 A^2)

    // affine grid from the actual pix_coords input (x fastest, then y, then z)
    const float ox = pix[0], oy = pix[1], oz = pix[2];
    const float sx = pix[3] - pix[0];
    const float sy = pix[NXg * 3 + 1] - pix[1];
    const float sz = pix[NXg * NYg * 3 + 2] - pix[2];

    // tile bounds in Angstroms (voxel centers)
    const float xlo = ox + (float)tx * sx,  xhi = ox + (float)(tx + 31) * sx;
    const float ylo = oy + (float)ty * sy,  yhi = oy + (float)(ty + 3) * sy;
    const float zlo = oz + (float)tz * sz,  zhi = oz + (float)(tz + 7) * sz;

    __syncthreads();   // acnt = 0 visible

    // ---- cull: exact box-sphere distance test, survivors -> LDS list ----
    for (int a = threadIdx.x; a < n_atoms; a += NTHR) {
        float ax = coords[3 * a + 0];
        float ay = coords[3 * a + 1];
        float az = coords[3 * a + 2];
        float dx = fmaxf(fmaxf(xlo - ax, ax - xhi), 0.0f);
        float dy = fmaxf(fmaxf(ylo - ay, ay - yhi), 0.0f);
        float dz = fmaxf(fmaxf(zlo - az, az - zhi), 0.0f);
        if (dx * dx + dy * dy + dz * dz <= R2) {
            int i = atomicAdd(&acnt, 1);           // LDS atomic
            if (i < CAP) alist[i] = make_float4(ax, ay, az, amps[a]);
        }
    }
    __syncthreads();
    const int n = min(acnt, CAP);                  // central tiles ~60-130 << 512

    // ---- accumulate: 4 consecutive-x voxels per thread, in registers ----
    const int lx = (threadIdx.x & 7) * 4;          // 8 x-runs per row of 32
    const int ly = (threadIdx.x >> 3) & 3;
    const int lz = threadIdx.x >> 5;
    const float vx0 = ox + (float)(tx + lx) * sx;
    const float vy  = oy + (float)(ty + ly) * sy;
    const float vz  = oz + (float)(tz + lz) * sz;
    const float run = 3.0f * sx;                   // x-run extent

    float acc0 = 0.f, acc1 = 0.f, acc2 = 0.f, acc3 = 0.f;
    for (int s = 0; s < n; ++s) {
        float4 A = alist[s];                       // same addr all lanes -> broadcast
        float dy  = vy - A.y;
        float dz  = vz - A.z;
        float d2c = dy * dy + dz * dz;
        float dx0 = vx0 - A.x;                     // leftmost x of the run
        float dx3 = dx0 + run;                     // rightmost x of the run
        // min |dx| over the run: 0 if the run straddles the atom
        float dxm = (dx0 <= 0.f && dx3 >= 0.f) ? 0.f
                                               : fminf(fabsf(dx0), fabsf(dx3));
        if (c * (d2c + dxm * dxm) > EXP_CUT) continue;  // coarse gate (often wave-uniform)

        float e0 = c * (d2c + dx0 * dx0);
        float d1 = dx0 + sx,        e1 = c * (d2c + d1 * d1);
        float d2 = dx0 + 2.f * sx,  e2 = c * (d2c + d2 * d2);
        float e3 = c * (d2c + dx3 * dx3);
        if (e0 <= EXP_CUT) acc0 += A.w * __expf(-e0);   // exact gate: same pair set
        if (e1 <= EXP_CUT) acc1 += A.w * __expf(-e1);   // as rounds 4/6
        if (e2 <= EXP_CUT) acc2 += A.w * __expf(-e2);
        if (e3 <= EXP_CUT) acc3 += A.w * __expf(-e3);
    }

    // ---- store: one float4 per thread, 16B aligned, rows contiguous ----
    const size_t gidx = ((size_t)(tz + lz) * NYg + (size_t)(ty + ly)) * NXg + (tx + lx);
    *(float4*)(out + gidx) = make_float4(acc0, acc1, acc2, acc3);
}

extern "C" void kernel_launch(void* const* d_in, const int* in_sizes, int n_in,
                              void* d_out, int out_size, void* d_ws, size_t ws_size,
                              hipStream_t stream)
{
    const float* coords = (const float*)d_in[0];   // (3000, 3) f32
    const float* amps   = (const float*)d_in[1];   // (3000,)  f32
    const float* pix    = (const float*)d_in[2];   // (2097152, 3) f32
    const int*   resp   = (const int*)d_in[3];     // scalar int
    float* out = (float*)d_out;                    // (1,128,128,128) f32

    const int n_atoms = in_sizes[1];

    // single kernel, single graph node: every voxel computed and stored exactly once.
    gather_gauss<<<NBLK, NTHR, 0, stream>>>(coords, amps, pix, resp, out, n_atoms);
}

// Round 8
// 15.062 us; speedup vs baseline: 1.3146x; 1.3146x over previous
//
#include <hip/hip_runtime.h>
#include <math.h>

// Gaussian map generator: out[z,y,x] = sum_a amp[a] * exp(-c * |r_voxel - r_atom|^2)
// c = 1/(2 sigma^2), sigma = resolution/(sqrt(2) pi).  res=2 -> c~2.467.
// Pair set: c*d^2 <= 12 (validated rounds 4/6/7: absmax 0.03125 vs threshold 0.4125).
//
// Round 8: round-4 two-node structure (best: 15.2us), trimmed.
// Overhead model (measured round 5: kernel 67us vs dur_us 80.5): graph-replay
// fixed overhead ~12.5us; zero ~1.3us (8.4MB @ 6.3TB/s); scatter ~1-2us.
// Gather variants (rounds 6/7) pay ~6us kernels -> strictly worse than zero+scatter.
// Trims: scatter blocks = 64 thr (1 wave; avg ~65-125 tasks/atom, so round-4's
// 2nd wave was idle ballast); zero = 1024 blocks x 2 unrolled float4 stores
// (regular stores keep lines in L2 for the atomics' RMW).

#define EXP_CUT 12.0f

__global__ __launch_bounds__(256)
void zero_out(float4* __restrict__ out)   // 524288 float4 = 1024 blk * 256 thr * 2
{
    int i = (blockIdx.x * 256 + threadIdx.x) * 2;
    out[i]     = make_float4(0.f, 0.f, 0.f, 0.f);
    out[i + 1] = make_float4(0.f, 0.f, 0.f, 0.f);
}

__global__ __launch_bounds__(64)
void scatter_gauss(const float* __restrict__ coords,
                   const float* __restrict__ amps,
                   const float* __restrict__ pix,
                   const int* __restrict__ resp,
                   float* __restrict__ out)
{
    const int NXg = 128, NYg = 128, NZg = 128;

    const int a = blockIdx.x;
    const float cx  = coords[a * 3 + 0];
    const float cy  = coords[a * 3 + 1];
    const float cz  = coords[a * 3 + 2];
    const float amp = amps[a];

    // sigma = res / (sqrt(2)*pi); c = 1/(2 sigma^2)
    const float res   = (float)resp[0];
    const float sigma = res / (sqrtf(2.0f) * 3.14159265358979323846f);
    const float c     = 1.0f / (2.0f * sigma * sigma);
    const float R     = sqrtf(EXP_CUT / c);      // ~2.2 A for res=2

    // affine grid from the actual pix_coords input (x fastest, then y, then z)
    const float ox = pix[0], oy = pix[1], oz = pix[2];
    const float sx = pix[3] - pix[0];
    const float sy = pix[NXg * 3 + 1] - pix[1];
    const float sz = pix[NXg * NYg * 3 + 2] - pix[2];

    int ixlo = max(0,       (int)ceilf ((cx - R - ox) / sx));
    int ixhi = min(NXg - 1, (int)floorf((cx + R - ox) / sx));
    int iylo = max(0,       (int)ceilf ((cy - R - oy) / sy));
    int iyhi = min(NYg - 1, (int)floorf((cy + R - oy) / sy));
    int izlo = max(0,       (int)ceilf ((cz - R - oz) / sz));
    int izhi = min(NZg - 1, (int)floorf((cz + R - oz) / sz));

    const int nx = ixhi - ixlo + 1;
    const int ny = iyhi - iylo + 1;
    const int nz = izhi - izlo + 1;
    if (nx <= 0 || ny <= 0 || nz <= 0) return;   // atom outside grid (uniform branch)

    const int tasks = nx * ny * nz;              // typically ~125 (box around sphere)
    for (int t = threadIdx.x; t < tasks; t += 64) {
        int dx = t % nx;          // x fastest -> consecutive lanes, consecutive addrs
        int r  = t / nx;          // nx,ny wave-uniform (one atom per block)
        int dy = r % ny;
        int dz = r / ny;
        float fx = ox + (float)(ixlo + dx) * sx - cx;
        float fy = oy + (float)(iylo + dy) * sy - cy;
        float fz = oz + (float)(izlo + dz) * sz - cz;
        float e  = c * (fx * fx + fy * fy + fz * fz);
        if (e <= EXP_CUT) {       // spherical gate: cube corners issue no atomic
            int idx = ((izlo + dz) * NYg + (iylo + dy)) * NXg + (ixlo + dx);
            atomicAdd(out + idx, amp * __expf(-e));
        }
    }
}

extern "C" void kernel_launch(void* const* d_in, const int* in_sizes, int n_in,
                              void* d_out, int out_size, void* d_ws, size_t ws_size,
                              hipStream_t stream)
{
    const float* coords = (const float*)d_in[0];   // (3000, 3) f32
    const float* amps   = (const float*)d_in[1];   // (3000,)  f32
    const float* pix    = (const float*)d_in[2];   // (2097152, 3) f32
    const int*   resp   = (const int*)d_in[3];     // scalar int
    float* out = (float*)d_out;                    // (1,128,128,128) f32

    const int n_atoms = in_sizes[1];

    // harness poisons d_out with 0xAA once and never re-poisons: zero every call.
    // 2097152 floats = 524288 float4 = 1024 blocks * 256 thr * 2.
    zero_out<<<1024, 256, 0, stream>>>((float4*)out);
    scatter_gauss<<<n_atoms, 64, 0, stream>>>(coords, amps, pix, resp, out);
}